// Round 7
// baseline (1929.815 us; speedup 1.0000x reference)
//
#include <hip/hip_runtime.h>
#include <hip/hip_bf16.h>

#define NN      2048
#define NSTEPS  2047
#define NPAIRS  1024
#define MROWS   8192

typedef __attribute__((ext_vector_type(8))) __bf16 bf16x8;
typedef __attribute__((ext_vector_type(4))) float  f32x4;
typedef __attribute__((ext_vector_type(2))) float  f32x2;

__device__ __forceinline__ unsigned short f2bf(float f) {
  unsigned int u = __float_as_uint(f);
  u += 0x7fffu + ((u >> 16) & 1u);   // RNE
  return (unsigned short)(u >> 16);
}

__device__ __forceinline__ void gload_lds16(const void* g, void* l) {
  __builtin_amdgcn_global_load_lds((const __attribute__((address_space(1))) void*)g,
                                   (__attribute__((address_space(3))) void*)l, 16, 0, 0);
}

// DPP wave-wide lane shifts (VALU pipe, no LDS). Verified in round 6.
template<int CTRL>
__device__ __forceinline__ float dppf(float v) {
  return __int_as_float(__builtin_amdgcn_update_dpp(
      __float_as_int(v), __float_as_int(v), CTRL, 0xf, 0xf, false));
}
#define DPP_UP 0x138   // wave_shr1: dst[i] = src[i-1]  (shfl_up 1)
#define DPP_DN 0x130   // wave_shl1: dst[i] = src[i+1]  (shfl_down 1)

// Packed fp32 math with op_sel broadcast from a (c,s) register pair.
// cs = {c, s}. pk_smul: {s,s}*v ; pk_cfma: {c,c}*v + a ; pk_cfma_neg: {c,c}*v - a.
__device__ __forceinline__ f32x2 pk_smul(f32x2 cs, f32x2 v) {
  f32x2 d;
  asm("v_pk_mul_f32 %0, %1, %2 op_sel:[1,0] op_sel_hi:[1,1]"
      : "=v"(d) : "v"(cs), "v"(v));
  return d;
}
__device__ __forceinline__ f32x2 pk_cfma(f32x2 cs, f32x2 v, f32x2 a) {
  f32x2 d;
  asm("v_pk_fma_f32 %0, %1, %2, %3 op_sel:[0,0,0] op_sel_hi:[0,1,1]"
      : "=v"(d) : "v"(cs), "v"(v), "v"(a));
  return d;
}
__device__ __forceinline__ f32x2 pk_cfma_neg(f32x2 cs, f32x2 v, f32x2 a) {
  f32x2 d;
  asm("v_pk_fma_f32 %0, %1, %2, %3 op_sel:[0,0,0] op_sel_hi:[0,1,1] neg_lo:[0,0,1] neg_hi:[0,0,1]"
      : "=v"(d) : "v"(cs), "v"(v), "v"(a));
  return d;
}

// ---- kernel 1: angles -> (cos,sin) table, layout cs[step][pair] (8 KB/step slice)
__global__ __launch_bounds__(256) void prep_kernel(
    const float* __restrict__ angles, float2* __restrict__ cs) {
  int idx = blockIdx.x * 256 + threadIdx.x;
  if (idx >= NSTEPS * NPAIRS) return;
  float s, c;
  sincosf(angles[idx], &s, &c);
  cs[idx] = make_float2(c, s);
}

// ---- kernel 2: x fp32 -> bf16 (vectorized)
__global__ __launch_bounds__(256) void cvt_kernel(
    const float4* __restrict__ x, ushort4* __restrict__ xb, int n4) {
  int idx = blockIdx.x * 256 + threadIdx.x;
  if (idx >= n4) return;
  float4 v = x[idx];
  ushort4 o;
  o.x = f2bf(v.x); o.y = f2bf(v.y); o.z = f2bf(v.z); o.w = f2bf(v.w);
  xb[idx] = o;
}

// ---- kernel 3: register-systolic build of U — WAVE-AUTONOMOUS ring (round-2
// geometry + round-6 DPP + pk-asm math). Each wave owns 2 rows (f32x2) across the
// whole 2047-position conveyor: 16 pairs/lane. No LDS, no barriers, no exchange.
// Reg mapping at step T (PHI=T&15): F elem e in FF[(e-T)&15], S elem e in SS[(e+T)&15].
// cs: 8 float4/lane/step, double-buffered (prefetch t+1 at start of step t).
__global__ __launch_bounds__(256, 1) void build_kernel(
    const char* __restrict__ csb, unsigned short* __restrict__ Ub) {
  const int tid  = threadIdx.x;
  const int lane = tid & 63;
  const int w    = blockIdx.x * 4 + (tid >> 6);   // wave id 0..1023
  const int rA = 2 * w, rB = 2 * w + 1;
  const bool l0 = (lane == 0), l63 = (lane == 63);

  // state: F elem e <-> pos p = 16*lane+e ; S elem e <-> pos 2047-p. .x=rA, .y=rB
  f32x2 FF[16], SS[16];
#pragma unroll
  for (int e = 0; e < 16; ++e) {
    const int p = 16 * lane + e, m = 2047 - p;
    FF[e] = (f32x2){(p == rA) ? 1.f : 0.f, (p == rB) ? 1.f : 0.f};
    SS[e] = (f32x2){(m == rA) ? 1.f : 0.f, (m == rB) ? 1.f : 0.f};
  }

  // cs: lane's 16 pairs = 128 B contiguous at slice_base + 128*lane
  float4 cvA[8], cvB[8];
  {
    const float4* p0 = (const float4*)(csb + 128 * lane);
#pragma unroll
    for (int j = 0; j < 8; ++j) cvA[j] = p0[j];   // slice 0
  }

#define PREF(NXT, TSLICE) { \
    const float4* p_ = (const float4*)(csb + (size_t)(TSLICE) * 8192 + 128 * lane); \
    _Pragma("unroll") for (int j_ = 0; j_ < 8; ++j_) NXT[j_] = p_[j_]; }

#define ROTALL(CUR) \
  _Pragma("unroll") for (int k_ = 0; k_ < 16; ++k_) { \
    const int rF_ = (k_ - PHI) & 15, rS_ = (k_ + PHI) & 15; \
    const f32x2 cp_ = ((const f32x2*)&CUR[k_ >> 1])[k_ & 1]; \
    const f32x2 t_ = pk_smul(cp_, SS[rS_]); \
    const f32x2 u_ = pk_smul(cp_, FF[rF_]); \
    FF[rF_] = pk_cfma(cp_, FF[rF_], t_); \
    SS[rS_] = pk_cfma_neg(cp_, SS[rS_], u_); \
  }

  // conveyor (round-2 verified logic): F flows +1, S flows -1; pos0 stationary;
  // lane0: new F(e=1 slot) <- old S(e=0); lane63: new S(e=15 slot) <- old F(e=15)
#define SHIFT() { \
    const int pF_ = (15 - PHI) & 15, pT_ = (16 - PHI) & 15; \
    const f32x2 Fo = FF[pF_], So = SS[PHI], St = FF[pT_]; \
    f32x2 fi, sd; \
    fi.x = dppf<DPP_UP>(Fo.x); fi.y = dppf<DPP_UP>(Fo.y); \
    sd.x = dppf<DPP_DN>(So.x); sd.y = dppf<DPP_DN>(So.y); \
    FF[pF_] = l0  ? St : fi; \
    SS[PHI] = l63 ? Fo : sd; \
    FF[pT_] = l0  ? So : FF[pT_]; \
  }

#define STEP(PHI_, CUR, NXT, TB) { \
    const int PHI = (PHI_); \
    PREF(NXT, (TB) + (PHI) + 1) \
    ROTALL(CUR) \
    SHIFT() }

  int tb = 0;
#pragma unroll 1
  for (int it = 0; it < 127; ++it, tb += 16) {
    STEP(0,  cvA, cvB, tb) STEP(1,  cvB, cvA, tb)
    STEP(2,  cvA, cvB, tb) STEP(3,  cvB, cvA, tb)
    STEP(4,  cvA, cvB, tb) STEP(5,  cvB, cvA, tb)
    STEP(6,  cvA, cvB, tb) STEP(7,  cvB, cvA, tb)
    STEP(8,  cvA, cvB, tb) STEP(9,  cvB, cvA, tb)
    STEP(10, cvA, cvB, tb) STEP(11, cvB, cvA, tb)
    STEP(12, cvA, cvB, tb) STEP(13, cvB, cvA, tb)
    STEP(14, cvA, cvB, tb) STEP(15, cvB, cvA, tb)
  }
  // tail: t = 2032..2046 (15 steps); last prefetch reads pad slice 2047
  STEP(0,  cvA, cvB, 2032) STEP(1,  cvB, cvA, 2032)
  STEP(2,  cvA, cvB, 2032) STEP(3,  cvB, cvA, 2032)
  STEP(4,  cvA, cvB, 2032) STEP(5,  cvB, cvA, 2032)
  STEP(6,  cvA, cvB, 2032) STEP(7,  cvB, cvA, 2032)
  STEP(8,  cvA, cvB, 2032) STEP(9,  cvB, cvA, 2032)
  STEP(10, cvA, cvB, 2032) STEP(11, cvB, cvA, 2032)
  STEP(12, cvA, cvB, 2032) STEP(13, cvB, cvA, 2032)
  STEP(14, cvA, cvB, 2032)

  // Readout at T=2047 (round-2 verified): F col 16l+e in FF[(e+1)&15];
  // S col 2047-(16l+e) in SS[(e-1)&15].
#pragma unroll
  for (int rr = 0; rr < 2; ++rr) {
    unsigned short* rowp = Ub + (size_t)(2 * w + rr) * NN;
    unsigned int uf[8], us[8];
#pragma unroll
    for (int j = 0; j < 8; ++j) {
      const float a0 = rr ? FF[(2*j + 1) & 15].y : FF[(2*j + 1) & 15].x;
      const float a1 = rr ? FF[(2*j + 2) & 15].y : FF[(2*j + 2) & 15].x;
      const float b0 = rr ? SS[(14 - 2*j) & 15].y : SS[(14 - 2*j) & 15].x;
      const float b1 = rr ? SS[(13 - 2*j) & 15].y : SS[(13 - 2*j) & 15].x;
      uf[j] = (unsigned)f2bf(a0) | ((unsigned)f2bf(a1) << 16);
      us[j] = (unsigned)f2bf(b0) | ((unsigned)f2bf(b1) << 16);
    }
    uint4* pF = (uint4*)(rowp + (lane << 4));
    pF[0] = make_uint4(uf[0], uf[1], uf[2], uf[3]);
    pF[1] = make_uint4(uf[4], uf[5], uf[6], uf[7]);
    uint4* pS = (uint4*)(rowp + (2032 - (lane << 4)));
    pS[0] = make_uint4(us[0], us[1], us[2], us[3]);
    pS[1] = make_uint4(us[4], us[5], us[6], us[7]);
  }
}

// ---- kernel 4: C = A * B^T + bias.  A = x_bf16 [8192][2048], B = U_bf16 [2048][2048]
#define BM 128
#define BN 128
#define BK 32

__global__ __launch_bounds__(256) void gemm_kernel(
    const unsigned short* __restrict__ A, const unsigned short* __restrict__ B,
    const float* __restrict__ bias, float* __restrict__ C) {
  __shared__ unsigned short As[BM * BK];
  __shared__ unsigned short Bs[BN * BK];
  const int tid  = threadIdx.x;
  const int lane = tid & 63;
  const int wave = tid >> 6;
  const int bm = blockIdx.x, bn = blockIdx.y;
  const int wm = wave & 1, wn = wave >> 1;

  const int srow = wave * 16 + (lane >> 2);
  const int scol = (lane & 3) * 8;
  const unsigned short* Ag = A + (size_t)(bm * BM + srow) * NN + scol;
  const unsigned short* Bg = B + (size_t)(bn * BN + srow) * NN + scol;

  const int fm = lane & 15;
  const int kb = lane >> 4;

  f32x4 acc[4][4];
#pragma unroll
  for (int a_ = 0; a_ < 4; ++a_)
#pragma unroll
    for (int b_ = 0; b_ < 4; ++b_) acc[a_][b_] = (f32x4){0.f, 0.f, 0.f, 0.f};

  for (int kt = 0; kt < NN / BK; ++kt) {
    const int k0 = kt * BK;
#pragma unroll
    for (int it = 0; it < 2; ++it) {
      gload_lds16(Ag + (size_t)(it * 64) * NN + k0, &As[wave * 512 + it * 2048]);
      gload_lds16(Bg + (size_t)(it * 64) * NN + k0, &Bs[wave * 512 + it * 2048]);
    }
    __syncthreads();

    bf16x8 af[4], bfr[4];
#pragma unroll
    for (int a_ = 0; a_ < 4; ++a_)
      af[a_] = *(const bf16x8*)&As[(wm * 64 + a_ * 16 + fm) * BK + kb * 8];
#pragma unroll
    for (int b_ = 0; b_ < 4; ++b_)
      bfr[b_] = *(const bf16x8*)&Bs[(wn * 64 + b_ * 16 + fm) * BK + kb * 8];
#pragma unroll
    for (int a_ = 0; a_ < 4; ++a_)
#pragma unroll
      for (int b_ = 0; b_ < 4; ++b_)
        acc[a_][b_] = __builtin_amdgcn_mfma_f32_16x16x32_bf16(af[a_], bfr[b_], acc[a_][b_], 0, 0, 0);
    __syncthreads();
  }

  const int row_in = (lane >> 4) * 4;
#pragma unroll
  for (int a_ = 0; a_ < 4; ++a_) {
#pragma unroll
    for (int b_ = 0; b_ < 4; ++b_) {
      int gn = bn * BN + wn * 64 + b_ * 16 + fm;
      float bv = bias[gn];
#pragma unroll
      for (int v = 0; v < 4; ++v) {
        int gm = bm * BM + wm * 64 + a_ * 16 + row_in + v;
        C[(size_t)gm * NN + gn] = acc[a_][b_][v] + bv;
      }
    }
  }
}

extern "C" void kernel_launch(void* const* d_in, const int* in_sizes, int n_in,
                              void* d_out, int out_size, void* d_ws, size_t ws_size,
                              hipStream_t stream) {
  const float* x      = (const float*)d_in[0];
  const float* angles = (const float*)d_in[1];
  const float* bias   = (const float*)d_in[2];
  float* out = (float*)d_out;

  char* ws = (char*)d_ws;
  char*           cs = ws;                                 // 2048 slices * 8KB = 16,777,216 B (slice 2047 = pad)
  unsigned short* xb = (unsigned short*)(ws + 16777216);   // 33,554,432 B
  unsigned short* Ub = (unsigned short*)(ws + 50331648);   //  8,388,608 B
  // total 58,720,256 B

  prep_kernel<<<dim3(8188), dim3(256), 0, stream>>>(angles, (float2*)cs);
  cvt_kernel<<<dim3(16384), dim3(256), 0, stream>>>((const float4*)x, (ushort4*)xb,
                                                    MROWS * NN / 4);
  build_kernel<<<dim3(256), dim3(256), 0, stream>>>(cs, Ub);
  gemm_kernel<<<dim3(MROWS / BM, NN / BN), dim3(256), 0, stream>>>(xb, Ub, bias, out);
}

// Round 8
// 930.810 us; speedup vs baseline: 2.0733x; 2.0733x over previous
//
#include <hip/hip_runtime.h>
#include <hip/hip_bf16.h>

#define NN      2048
#define NSTEPS  2047
#define NPAIRS  1024
#define MROWS   8192

typedef __attribute__((ext_vector_type(8))) __bf16 bf16x8;
typedef __attribute__((ext_vector_type(4))) float  f32x4;
typedef __attribute__((ext_vector_type(2))) float  f32x2;

__device__ __forceinline__ unsigned short f2bf(float f) {
  unsigned int u = __float_as_uint(f);
  u += 0x7fffu + ((u >> 16) & 1u);   // RNE
  return (unsigned short)(u >> 16);
}

__device__ __forceinline__ void gload_lds16(const void* g, void* l) {
  __builtin_amdgcn_global_load_lds((const __attribute__((address_space(1))) void*)g,
                                   (__attribute__((address_space(3))) void*)l, 16, 0, 0);
}

// DPP wave-wide lane shifts (VALU pipe, no LDS). Verified rounds 6-7.
template<int CTRL>
__device__ __forceinline__ float dppf(float v) {
  return __int_as_float(__builtin_amdgcn_update_dpp(
      __float_as_int(v), __float_as_int(v), CTRL, 0xf, 0xf, false));
}
#define DPP_UP 0x138   // wave_shr1: dst[i] = src[i-1]  (shfl_up 1)
#define DPP_DN 0x130   // wave_shl1: dst[i] = src[i+1]  (shfl_down 1)

// Packed fp32 math with op_sel broadcast from a (c,s) register pair. Verified round 7.
__device__ __forceinline__ f32x2 pk_smul(f32x2 cs, f32x2 v) {
  f32x2 d;
  asm("v_pk_mul_f32 %0, %1, %2 op_sel:[1,0] op_sel_hi:[1,1]"
      : "=v"(d) : "v"(cs), "v"(v));
  return d;
}
__device__ __forceinline__ f32x2 pk_cfma(f32x2 cs, f32x2 v, f32x2 a) {
  f32x2 d;
  asm("v_pk_fma_f32 %0, %1, %2, %3 op_sel:[0,0,0] op_sel_hi:[0,1,1]"
      : "=v"(d) : "v"(cs), "v"(v), "v"(a));
  return d;
}
__device__ __forceinline__ f32x2 pk_cfma_neg(f32x2 cs, f32x2 v, f32x2 a) {
  f32x2 d;
  asm("v_pk_fma_f32 %0, %1, %2, %3 op_sel:[0,0,0] op_sel_hi:[0,1,1] neg_lo:[0,0,1] neg_hi:[0,0,1]"
      : "=v"(d) : "v"(cs), "v"(v), "v"(a));
  return d;
}

// ---- kernel 1: angles -> (cos,sin) table, layout cs[step][pair] (8 KB/step slice)
__global__ __launch_bounds__(256) void prep_kernel(
    const float* __restrict__ angles, float2* __restrict__ cs) {
  int idx = blockIdx.x * 256 + threadIdx.x;
  if (idx >= NSTEPS * NPAIRS) return;
  float s, c;
  sincosf(angles[idx], &s, &c);
  cs[idx] = make_float2(c, s);
}

// ---- kernel 2: x fp32 -> bf16 (vectorized)
__global__ __launch_bounds__(256) void cvt_kernel(
    const float4* __restrict__ x, ushort4* __restrict__ xb, int n4) {
  int idx = blockIdx.x * 256 + threadIdx.x;
  if (idx >= n4) return;
  float4 v = x[idx];
  ushort4 o;
  o.x = f2bf(v.x); o.y = f2bf(v.y); o.z = f2bf(v.z); o.w = f2bf(v.w);
  xb[idx] = o;
}

// ---- kernel 3: register-systolic build of U (position space, static pairing).
// Round-5 skeleton (8-wave WG = q-quarter x g-rowgroup, verified boundary logic)
// + round-7 pk-asm rotations + round-6 DPP shifts + direct global->reg cs loads
// (no LDS cv staging: LDS pipe carries only the 192B exch). 512 WGs x 8 waves =
// 4096 waves = 4/SIMD. Reg map at step T (PHI=T&3): F elem e <-> reg (e-T)&3,
// S elem e <-> reg (e+T)&3.
__global__ __launch_bounds__(512, 4) void build_kernel(
    const char* __restrict__ csb, unsigned short* __restrict__ Ub) {
  __shared__ f32x2 exch[2][2][2][3];   // [parity][g][0=F fwd,1=S bwd][slot]

  const int tid  = threadIdx.x;
  const int lane = tid & 63;
  const int wv   = tid >> 6;
  const int q    = wv & 3;                 // pair-quarter
  const int g    = wv >> 2;                // row-group
  const int r0   = blockIdx.x * 4 + 2 * g; // rows r0, r0+1
  const bool l0 = (lane == 0), l63 = (lane == 63);
  const bool q0 = (q == 0), q3 = (q == 3);

  // state: elem e <-> pair p = 256q + 4*lane + e; .x = row r0, .y = row r0+1
  f32x2 FF[4], SS[4];
#pragma unroll
  for (int e = 0; e < 4; ++e) {
    const int p = 256 * q + 4 * lane + e, m = 2047 - p;
    FF[e] = (f32x2){(p == r0) ? 1.f : 0.f, (p == r0 + 1) ? 1.f : 0.f};
    SS[e] = (f32x2){(m == r0) ? 1.f : 0.f, (m == r0 + 1) ? 1.f : 0.f};
  }

  // cs: lane's 4 pairs = 32B contiguous at slice_base + 2048q + 32*lane
  const char* gpA = csb + 2048 * q + 32 * lane;   // even slices
  const char* gpB = gpA + 8192;                   // odd slices
  float4 cvA0 = ((const float4*)gpA)[0], cvA1 = ((const float4*)gpA)[1];  // slice 0
  float4 cvB0, cvB1;
  gpA += 16384;                                    // -> slice 2

#define ROT1(E, CP) { \
    const int rF = ((E) - PHI) & 3, rS = ((E) + PHI) & 3; \
    const f32x2 t_ = pk_smul(CP, SS[rS]); \
    const f32x2 u_ = pk_smul(CP, FF[rF]); \
    FF[rF] = pk_cfma(CP, FF[rF], t_); \
    SS[rS] = pk_cfma_neg(CP, SS[rS], u_); }

#define STEP(PHI_, CUR0, CUR1, NXT0, NXT1, GPN) { \
    const int PHI = (PHI_); \
    const int PAR = PHI & 1; \
    const int pF = (3 - PHI) & 3, pT = (4 - PHI) & 3; \
    ROT1(0, ((f32x2){CUR0.x, CUR0.y})) ROT1(1, ((f32x2){CUR0.z, CUR0.w})) \
    ROT1(2, ((f32x2){CUR1.x, CUR1.y})) ROT1(3, ((f32x2){CUR1.z, CUR1.w})) \
    const f32x2 Fo = FF[pF], So = SS[PHI], St = FF[pT]; \
    f32x2 fi, sd; \
    fi.x = dppf<DPP_UP>(Fo.x); fi.y = dppf<DPP_UP>(Fo.y); \
    sd.x = dppf<DPP_DN>(So.x); sd.y = dppf<DPP_DN>(So.y); \
    if (!q3 && l63) exch[PAR][g][0][q]     = Fo; \
    if (!q0 && l0)  exch[PAR][g][1][q - 1] = So; \
    NXT0 = ((const float4*)GPN)[0]; NXT1 = ((const float4*)GPN)[1]; \
    GPN += 16384;                                  /* prefetch slice t+1 */ \
    asm volatile("s_waitcnt lgkmcnt(0)" ::: "memory"); \
    __builtin_amdgcn_s_barrier(); \
    __builtin_amdgcn_sched_barrier(0); \
    f32x2 eF = {0.f, 0.f}, eS = {0.f, 0.f}; \
    if (!q0 && l0)  eF = exch[PAR][g][0][q - 1]; \
    if (!q3 && l63) eS = exch[PAR][g][1][q]; \
    FF[pF]  = l0  ? (q0 ? St : eF) : fi; \
    SS[PHI] = l63 ? (q3 ? Fo : eS) : sd; \
    if (q0) { FF[pT] = l0 ? So : FF[pT]; } \
  }

#pragma unroll 1
  for (int it = 0; it < 511; ++it) {
    STEP(0, cvA0, cvA1, cvB0, cvB1, gpB)
    STEP(1, cvB0, cvB1, cvA0, cvA1, gpA)
    STEP(2, cvA0, cvA1, cvB0, cvB1, gpB)
    STEP(3, cvB0, cvB1, cvA0, cvA1, gpA)
  }
  // tail: t = 2044, 2045, 2046 (last prefetch reads pad slice 2047, never used)
  STEP(0, cvA0, cvA1, cvB0, cvB1, gpB)
  STEP(1, cvB0, cvB1, cvA0, cvA1, gpA)
  STEP(2, cvA0, cvA1, cvB0, cvB1, gpB)

  // Readout at T=2047 (cycle closed; 2047 mod 4 = 3) — round-5 verified mapping:
  // F elem e in reg (e+1)&3, col 256q+4l+e; S elem e in reg (e-1)&3, col 2047-(256q+4l+e)
  const int cf  = 256 * q + 4 * lane;
  const int cs_ = 2044 - cf;
#pragma unroll
  for (int rr = 0; rr < 2; ++rr) {
    unsigned short* rp = Ub + (size_t)(r0 + rr) * NN;
    const float f1 = rr ? FF[1].y : FF[1].x, f2 = rr ? FF[2].y : FF[2].x;
    const float f3 = rr ? FF[3].y : FF[3].x, f0 = rr ? FF[0].y : FF[0].x;
    const float s2 = rr ? SS[2].y : SS[2].x, s1 = rr ? SS[1].y : SS[1].x;
    const float s0 = rr ? SS[0].y : SS[0].x, s3 = rr ? SS[3].y : SS[3].x;
    const unsigned uf0 = (unsigned)f2bf(f1) | ((unsigned)f2bf(f2) << 16);
    const unsigned uf1 = (unsigned)f2bf(f3) | ((unsigned)f2bf(f0) << 16);
    const unsigned us0 = (unsigned)f2bf(s2) | ((unsigned)f2bf(s1) << 16);
    const unsigned us1 = (unsigned)f2bf(s0) | ((unsigned)f2bf(s3) << 16);
    *(uint2*)(rp + cf)  = make_uint2(uf0, uf1);
    *(uint2*)(rp + cs_) = make_uint2(us0, us1);
  }
}

// ---- kernel 4: C = A * B^T + bias.  A = x_bf16 [8192][2048], B = U_bf16 [2048][2048]
#define BM 128
#define BN 128
#define BK 32

__global__ __launch_bounds__(256) void gemm_kernel(
    const unsigned short* __restrict__ A, const unsigned short* __restrict__ B,
    const float* __restrict__ bias, float* __restrict__ C) {
  __shared__ unsigned short As[BM * BK];
  __shared__ unsigned short Bs[BN * BK];
  const int tid  = threadIdx.x;
  const int lane = tid & 63;
  const int wave = tid >> 6;
  const int bm = blockIdx.x, bn = blockIdx.y;
  const int wm = wave & 1, wn = wave >> 1;

  const int srow = wave * 16 + (lane >> 2);
  const int scol = (lane & 3) * 8;
  const unsigned short* Ag = A + (size_t)(bm * BM + srow) * NN + scol;
  const unsigned short* Bg = B + (size_t)(bn * BN + srow) * NN + scol;

  const int fm = lane & 15;
  const int kb = lane >> 4;

  f32x4 acc[4][4];
#pragma unroll
  for (int a_ = 0; a_ < 4; ++a_)
#pragma unroll
    for (int b_ = 0; b_ < 4; ++b_) acc[a_][b_] = (f32x4){0.f, 0.f, 0.f, 0.f};

  for (int kt = 0; kt < NN / BK; ++kt) {
    const int k0 = kt * BK;
#pragma unroll
    for (int it = 0; it < 2; ++it) {
      gload_lds16(Ag + (size_t)(it * 64) * NN + k0, &As[wave * 512 + it * 2048]);
      gload_lds16(Bg + (size_t)(it * 64) * NN + k0, &Bs[wave * 512 + it * 2048]);
    }
    __syncthreads();

    bf16x8 af[4], bfr[4];
#pragma unroll
    for (int a_ = 0; a_ < 4; ++a_)
      af[a_] = *(const bf16x8*)&As[(wm * 64 + a_ * 16 + fm) * BK + kb * 8];
#pragma unroll
    for (int b_ = 0; b_ < 4; ++b_)
      bfr[b_] = *(const bf16x8*)&Bs[(wn * 64 + b_ * 16 + fm) * BK + kb * 8];
#pragma unroll
    for (int a_ = 0; a_ < 4; ++a_)
#pragma unroll
      for (int b_ = 0; b_ < 4; ++b_)
        acc[a_][b_] = __builtin_amdgcn_mfma_f32_16x16x32_bf16(af[a_], bfr[b_], acc[a_][b_], 0, 0, 0);
    __syncthreads();
  }

  const int row_in = (lane >> 4) * 4;
#pragma unroll
  for (int a_ = 0; a_ < 4; ++a_) {
#pragma unroll
    for (int b_ = 0; b_ < 4; ++b_) {
      int gn = bn * BN + wn * 64 + b_ * 16 + fm;
      float bv = bias[gn];
#pragma unroll
      for (int v = 0; v < 4; ++v) {
        int gm = bm * BM + wm * 64 + a_ * 16 + row_in + v;
        C[(size_t)gm * NN + gn] = acc[a_][b_][v] + bv;
      }
    }
  }
}

extern "C" void kernel_launch(void* const* d_in, const int* in_sizes, int n_in,
                              void* d_out, int out_size, void* d_ws, size_t ws_size,
                              hipStream_t stream) {
  const float* x      = (const float*)d_in[0];
  const float* angles = (const float*)d_in[1];
  const float* bias   = (const float*)d_in[2];
  float* out = (float*)d_out;

  char* ws = (char*)d_ws;
  char*           cs = ws;                                 // 2048 slices * 8KB = 16,777,216 B (slice 2047 = pad)
  unsigned short* xb = (unsigned short*)(ws + 16777216);   // 33,554,432 B
  unsigned short* Ub = (unsigned short*)(ws + 50331648);   //  8,388,608 B
  // total 58,720,256 B

  prep_kernel<<<dim3(8188), dim3(256), 0, stream>>>(angles, (float2*)cs);
  cvt_kernel<<<dim3(16384), dim3(256), 0, stream>>>((const float4*)x, (ushort4*)xb,
                                                    MROWS * NN / 4);
  build_kernel<<<dim3(512), dim3(512), 0, stream>>>(cs, Ub);
  gemm_kernel<<<dim3(MROWS / BM, NN / BN), dim3(256), 0, stream>>>(xb, Ub, bias, out);
}

// Round 9
// 903.639 us; speedup vs baseline: 2.1356x; 1.0301x over previous
//
#include <hip/hip_runtime.h>
#include <hip/hip_bf16.h>

#define NN      2048
#define NSTEPS  2047
#define NPAIRS  1024
#define MROWS   8192

typedef __attribute__((ext_vector_type(8))) __bf16 bf16x8;
typedef __attribute__((ext_vector_type(4))) float  f32x4;
typedef __attribute__((ext_vector_type(2))) float  f32x2;

__device__ __forceinline__ unsigned short f2bf(float f) {
  unsigned int u = __float_as_uint(f);
  u += 0x7fffu + ((u >> 16) & 1u);   // RNE
  return (unsigned short)(u >> 16);
}

__device__ __forceinline__ void gload_lds16(const void* g, void* l) {
  __builtin_amdgcn_global_load_lds((const __attribute__((address_space(1))) void*)g,
                                   (__attribute__((address_space(3))) void*)l, 16, 0, 0);
}

// DPP wave-wide lane shifts (VALU pipe, no LDS). Verified rounds 6-8.
template<int CTRL>
__device__ __forceinline__ float dppf(float v) {
  return __int_as_float(__builtin_amdgcn_update_dpp(
      __float_as_int(v), __float_as_int(v), CTRL, 0xf, 0xf, false));
}
#define DPP_UP 0x138   // wave_shr1: dst[i] = src[i-1]  (shfl_up 1)
#define DPP_DN 0x130   // wave_shl1: dst[i] = src[i+1]  (shfl_down 1)

// Packed fp32 math with op_sel broadcast from a (c,s) register pair. Verified rounds 7-8.
__device__ __forceinline__ f32x2 pk_smul(f32x2 cs, f32x2 v) {
  f32x2 d;
  asm("v_pk_mul_f32 %0, %1, %2 op_sel:[1,0] op_sel_hi:[1,1]"
      : "=v"(d) : "v"(cs), "v"(v));
  return d;
}
__device__ __forceinline__ f32x2 pk_cfma(f32x2 cs, f32x2 v, f32x2 a) {
  f32x2 d;
  asm("v_pk_fma_f32 %0, %1, %2, %3 op_sel:[0,0,0] op_sel_hi:[0,1,1]"
      : "=v"(d) : "v"(cs), "v"(v), "v"(a));
  return d;
}
__device__ __forceinline__ f32x2 pk_cfma_neg(f32x2 cs, f32x2 v, f32x2 a) {
  f32x2 d;
  asm("v_pk_fma_f32 %0, %1, %2, %3 op_sel:[0,0,0] op_sel_hi:[0,1,1] neg_lo:[0,0,1] neg_hi:[0,0,1]"
      : "=v"(d) : "v"(cs), "v"(v), "v"(a));
  return d;
}

// ---- kernel 1: angles -> (cos,sin) table, layout cs[step][pair] (8 KB/step slice)
__global__ __launch_bounds__(256) void prep_kernel(
    const float* __restrict__ angles, float2* __restrict__ cs) {
  int idx = blockIdx.x * 256 + threadIdx.x;
  if (idx >= NSTEPS * NPAIRS) return;
  float s, c;
  sincosf(angles[idx], &s, &c);
  cs[idx] = make_float2(c, s);
}

// ---- kernel 2: x fp32 -> bf16 (vectorized)
__global__ __launch_bounds__(256) void cvt_kernel(
    const float4* __restrict__ x, ushort4* __restrict__ xb, int n4) {
  int idx = blockIdx.x * 256 + threadIdx.x;
  if (idx >= n4) return;
  float4 v = x[idx];
  ushort4 o;
  o.x = f2bf(v.x); o.y = f2bf(v.y); o.z = f2bf(v.z); o.w = f2bf(v.w);
  xb[idx] = o;
}

// ---- kernel 3: register-systolic build of U (position space, static pairing).
// Round-8 skeleton (Q=4 quarter-waves, verified boundary/exchange/parity logic)
// with R=4 rows/wave (round-4's verified A/B state doubling): WG = 4 waves owns
// rows 4b..4b+3 (A = rows 0-1, B = rows 2-3 as f32x2). 512 WGs -> 2048 waves,
// 2/SIMD. pk-asm rotations + DPP shifts + direct global->reg cs loads,
// prefetched TWO slices deep to cover L2 latency at low occupancy.
__global__ __launch_bounds__(256, 2) void build_kernel(
    const char* __restrict__ csb, unsigned short* __restrict__ Ub) {
  __shared__ float4 exF[2][3], exS[2][3];   // [parity][boundary slot]

  const int tid  = threadIdx.x;
  const int lane = tid & 63;
  const int q    = tid >> 6;               // pair-quarter
  const int r0   = blockIdx.x * 4;         // rows r0..r0+3
  const bool l0 = (lane == 0), l63 = (lane == 63);
  const bool q0 = (q == 0), q3 = (q == 3);

  // state: elem e <-> pair p = 256q + 4*lane + e; A = rows r0,r0+1; B = rows r0+2,r0+3
  f32x2 FA[4], FB[4], SA[4], SB[4];
#pragma unroll
  for (int e = 0; e < 4; ++e) {
    const int p = 256 * q + 4 * lane + e, m = 2047 - p;
    FA[e] = (f32x2){(p == r0) ? 1.f : 0.f, (p == r0 + 1) ? 1.f : 0.f};
    FB[e] = (f32x2){(p == r0 + 2) ? 1.f : 0.f, (p == r0 + 3) ? 1.f : 0.f};
    SA[e] = (f32x2){(m == r0) ? 1.f : 0.f, (m == r0 + 1) ? 1.f : 0.f};
    SB[e] = (f32x2){(m == r0 + 2) ? 1.f : 0.f, (m == r0 + 3) ? 1.f : 0.f};
  }

  // cs: lane's 4 pairs = 32B contiguous at slice_base + 2048q + 32*lane.
  // Double-buffered by step parity, each buffer prefetched 2 slices ahead.
  const char* gpE = csb + 2048 * q + 32 * lane;   // even slices
  const char* gpO = gpE + 8192;                   // odd slices
  float4 cvE0 = ((const float4*)gpE)[0], cvE1 = ((const float4*)gpE)[1];  // slice 0
  float4 cvO0 = ((const float4*)gpO)[0], cvO1 = ((const float4*)gpO)[1];  // slice 1
  gpE += 16384; gpO += 16384;                     // -> slices 2, 3

#define ROT1(E, CP) { \
    const int rF = ((E) - PHI) & 3, rS = ((E) + PHI) & 3; \
    const f32x2 cp_ = (CP); \
    const f32x2 tA = pk_smul(cp_, SA[rS]); \
    const f32x2 uA = pk_smul(cp_, FA[rF]); \
    FA[rF] = pk_cfma(cp_, FA[rF], tA); \
    SA[rS] = pk_cfma_neg(cp_, SA[rS], uA); \
    const f32x2 tB = pk_smul(cp_, SB[rS]); \
    const f32x2 uB = pk_smul(cp_, FB[rF]); \
    FB[rF] = pk_cfma(cp_, FB[rF], tB); \
    SB[rS] = pk_cfma_neg(cp_, SB[rS], uB); }

#define STEP(PHI_, C0, C1, GP) { \
    const int PHI = (PHI_); \
    const int PAR = PHI & 1; \
    const int pF = (3 - PHI) & 3, pT = (4 - PHI) & 3; \
    ROT1(0, ((f32x2){C0.x, C0.y})) ROT1(1, ((f32x2){C0.z, C0.w})) \
    ROT1(2, ((f32x2){C1.x, C1.y})) ROT1(3, ((f32x2){C1.z, C1.w})) \
    const f32x2 FoA = FA[pF], FoB = FB[pF]; \
    const f32x2 SoA = SA[PHI], SoB = SB[PHI]; \
    const f32x2 StA = FA[pT], StB = FB[pT]; \
    f32x2 fiA, fiB, sdA, sdB; \
    fiA.x = dppf<DPP_UP>(FoA.x); fiA.y = dppf<DPP_UP>(FoA.y); \
    fiB.x = dppf<DPP_UP>(FoB.x); fiB.y = dppf<DPP_UP>(FoB.y); \
    sdA.x = dppf<DPP_DN>(SoA.x); sdA.y = dppf<DPP_DN>(SoA.y); \
    sdB.x = dppf<DPP_DN>(SoB.x); sdB.y = dppf<DPP_DN>(SoB.y); \
    if (!q3 && l63) exF[PAR][q]     = make_float4(FoA.x, FoA.y, FoB.x, FoB.y); \
    if (!q0 && l0)  exS[PAR][q - 1] = make_float4(SoA.x, SoA.y, SoB.x, SoB.y); \
    C0 = ((const float4*)GP)[0]; C1 = ((const float4*)GP)[1]; \
    GP += 16384;                                   /* prefetch slice t+2 */ \
    asm volatile("s_waitcnt lgkmcnt(0)" ::: "memory"); \
    __builtin_amdgcn_s_barrier(); \
    __builtin_amdgcn_sched_barrier(0); \
    float4 eF = make_float4(0.f, 0.f, 0.f, 0.f), eS = eF; \
    if (!q0 && l0)  eF = exF[PAR][q - 1]; \
    if (!q3 && l63) eS = exS[PAR][q]; \
    FA[pF]  = l0  ? (q0 ? StA : (f32x2){eF.x, eF.y}) : fiA; \
    FB[pF]  = l0  ? (q0 ? StB : (f32x2){eF.z, eF.w}) : fiB; \
    SA[PHI] = l63 ? (q3 ? FoA : (f32x2){eS.x, eS.y}) : sdA; \
    SB[PHI] = l63 ? (q3 ? FoB : (f32x2){eS.z, eS.w}) : sdB; \
    if (q0) { FA[pT] = l0 ? SoA : FA[pT]; FB[pT] = l0 ? SoB : FB[pT]; } \
  }

#pragma unroll 1
  for (int it = 0; it < 511; ++it) {
    STEP(0, cvE0, cvE1, gpE)
    STEP(1, cvO0, cvO1, gpO)
    STEP(2, cvE0, cvE1, gpE)
    STEP(3, cvO0, cvO1, gpO)
  }
  // tail: t = 2044, 2045, 2046 (prefetches reach pad slices 2046..2048 area; never consumed)
  STEP(0, cvE0, cvE1, gpE)
  STEP(1, cvO0, cvO1, gpO)
  STEP(2, cvE0, cvE1, gpE)

  // Readout at T=2047 (cycle closed; 2047 mod 4 = 3) — round-5/8 verified mapping:
  // F elem e in reg (e+1)&3, col 256q+4l+e; S elem e in reg (e-1)&3, col 2047-(256q+4l+e)
  const int cf  = 256 * q + 4 * lane;
  const int cs_ = 2044 - cf;
#pragma unroll
  for (int rr = 0; rr < 4; ++rr) {
    unsigned short* rp = Ub + (size_t)(r0 + rr) * NN;
    const f32x2* Fr = (rr < 2) ? FA : FB;
    const f32x2* Sr = (rr < 2) ? SA : SB;
    const bool hi = (rr & 1);
    const float f1 = hi ? Fr[1].y : Fr[1].x, f2 = hi ? Fr[2].y : Fr[2].x;
    const float f3 = hi ? Fr[3].y : Fr[3].x, f0 = hi ? Fr[0].y : Fr[0].x;
    const float s2 = hi ? Sr[2].y : Sr[2].x, s1 = hi ? Sr[1].y : Sr[1].x;
    const float s0 = hi ? Sr[0].y : Sr[0].x, s3 = hi ? Sr[3].y : Sr[3].x;
    const unsigned uf0 = (unsigned)f2bf(f1) | ((unsigned)f2bf(f2) << 16);
    const unsigned uf1 = (unsigned)f2bf(f3) | ((unsigned)f2bf(f0) << 16);
    const unsigned us0 = (unsigned)f2bf(s2) | ((unsigned)f2bf(s1) << 16);
    const unsigned us1 = (unsigned)f2bf(s0) | ((unsigned)f2bf(s3) << 16);
    *(uint2*)(rp + cf)  = make_uint2(uf0, uf1);
    *(uint2*)(rp + cs_) = make_uint2(us0, us1);
  }
}

// ---- kernel 4: C = A * B^T + bias.  A = x_bf16 [8192][2048], B = U_bf16 [2048][2048]
#define BM 128
#define BN 128
#define BK 32

__global__ __launch_bounds__(256) void gemm_kernel(
    const unsigned short* __restrict__ A, const unsigned short* __restrict__ B,
    const float* __restrict__ bias, float* __restrict__ C) {
  __shared__ unsigned short As[BM * BK];
  __shared__ unsigned short Bs[BN * BK];
  const int tid  = threadIdx.x;
  const int lane = tid & 63;
  const int wave = tid >> 6;
  const int bm = blockIdx.x, bn = blockIdx.y;
  const int wm = wave & 1, wn = wave >> 1;

  const int srow = wave * 16 + (lane >> 2);
  const int scol = (lane & 3) * 8;
  const unsigned short* Ag = A + (size_t)(bm * BM + srow) * NN + scol;
  const unsigned short* Bg = B + (size_t)(bn * BN + srow) * NN + scol;

  const int fm = lane & 15;
  const int kb = lane >> 4;

  f32x4 acc[4][4];
#pragma unroll
  for (int a_ = 0; a_ < 4; ++a_)
#pragma unroll
    for (int b_ = 0; b_ < 4; ++b_) acc[a_][b_] = (f32x4){0.f, 0.f, 0.f, 0.f};

  for (int kt = 0; kt < NN / BK; ++kt) {
    const int k0 = kt * BK;
#pragma unroll
    for (int it = 0; it < 2; ++it) {
      gload_lds16(Ag + (size_t)(it * 64) * NN + k0, &As[wave * 512 + it * 2048]);
      gload_lds16(Bg + (size_t)(it * 64) * NN + k0, &Bs[wave * 512 + it * 2048]);
    }
    __syncthreads();

    bf16x8 af[4], bfr[4];
#pragma unroll
    for (int a_ = 0; a_ < 4; ++a_)
      af[a_] = *(const bf16x8*)&As[(wm * 64 + a_ * 16 + fm) * BK + kb * 8];
#pragma unroll
    for (int b_ = 0; b_ < 4; ++b_)
      bfr[b_] = *(const bf16x8*)&Bs[(wn * 64 + b_ * 16 + fm) * BK + kb * 8];
#pragma unroll
    for (int a_ = 0; a_ < 4; ++a_)
#pragma unroll
      for (int b_ = 0; b_ < 4; ++b_)
        acc[a_][b_] = __builtin_amdgcn_mfma_f32_16x16x32_bf16(af[a_], bfr[b_], acc[a_][b_], 0, 0, 0);
    __syncthreads();
  }

  const int row_in = (lane >> 4) * 4;
#pragma unroll
  for (int a_ = 0; a_ < 4; ++a_) {
#pragma unroll
    for (int b_ = 0; b_ < 4; ++b_) {
      int gn = bn * BN + wn * 64 + b_ * 16 + fm;
      float bv = bias[gn];
#pragma unroll
      for (int v = 0; v < 4; ++v) {
        int gm = bm * BM + wm * 64 + a_ * 16 + row_in + v;
        C[(size_t)gm * NN + gn] = acc[a_][b_][v] + bv;
      }
    }
  }
}

extern "C" void kernel_launch(void* const* d_in, const int* in_sizes, int n_in,
                              void* d_out, int out_size, void* d_ws, size_t ws_size,
                              hipStream_t stream) {
  const float* x      = (const float*)d_in[0];
  const float* angles = (const float*)d_in[1];
  const float* bias   = (const float*)d_in[2];
  float* out = (float*)d_out;

  char* ws = (char*)d_ws;
  char*           cs = ws;                                 // 2049 slices * 8KB = 16,785,408 B (2047 real + 2 pad)
  unsigned short* xb = (unsigned short*)(ws + 16785408);   // 33,554,432 B
  unsigned short* Ub = (unsigned short*)(ws + 50339840);   //  8,388,608 B
  // total 58,728,448 B

  prep_kernel<<<dim3(8188), dim3(256), 0, stream>>>(angles, (float2*)cs);
  cvt_kernel<<<dim3(16384), dim3(256), 0, stream>>>((const float4*)x, (ushort4*)xb,
                                                    MROWS * NN / 4);
  build_kernel<<<dim3(512), dim3(256), 0, stream>>>(cs, Ub);
  gemm_kernel<<<dim3(MROWS / BM, NN / BN), dim3(256), 0, stream>>>(xb, Ub, bias, out);
}